// Round 5
// baseline (442.507 us; speedup 1.0000x reference)
//
#include <hip/hip_runtime.h>

#define BATCH 65536

typedef float f32x4 __attribute__((ext_vector_type(4)));
typedef _Float16 f16x8 __attribute__((ext_vector_type(8)));

__device__ __forceinline__ void async_ld16(const void* g, void* l) {
  __builtin_amdgcn_global_load_lds(
      (const __attribute__((address_space(1))) void*)g,
      (__attribute__((address_space(3))) void*)l, 16, 0, 0);
}

__device__ __forceinline__ float act_f(float x, float a0, float a1, float a2,
                                       float a3, float a4) {
  float ax = fabsf(x);
  float e = __builtin_amdgcn_exp2f(ax * -2.8853900817779268f);
  float th = (1.0f - e) * __builtin_amdgcn_rcpf(1.0f + e);
  th = copysignf(th, x);
  float arg = fmaf(a1, x, a2);
  float rev = arg * 0.15915494309189535f;
  rev -= floorf(rev);
  float s = __builtin_amdgcn_sinf(rev);
  return fmaf(a3, x, fmaf(a0 * th, s, a4));
}

// split + transpose weights: W[K][N] fp32 -> Wt_hi/lo[N][K] fp16 (packed)
__global__ __launch_bounds__(256) void splitT_k(const float* __restrict__ W,
                                                _Float16* __restrict__ hi,
                                                _Float16* __restrict__ lo,
                                                int K, int N) {
  const int i = blockIdx.x * 256 + threadIdx.x;
  if (i >= K * N) return;
  const int k = i / N, n = i % N;
  const float w = W[i];
  const _Float16 h = (_Float16)w;
  hi[(size_t)n * K + k] = h;
  lo[(size_t)n * K + k] = (_Float16)(w - (float)h);
}

__device__ __forceinline__ f32x4 mfma3(f16x8 ah, f16x8 al, f16x8 bh, f16x8 bl,
                                       f32x4 c) {
  c = __builtin_amdgcn_mfma_f32_16x16x32_f16(ah, bh, c, 0, 0, 0);
  c = __builtin_amdgcn_mfma_f32_16x16x32_f16(ah, bl, c, 0, 0, 0);
  c = __builtin_amdgcn_mfma_f32_16x16x32_f16(al, bh, c, 0, 0, 0);
  return c;
}

// C = A @ B, block tile 128 rows x 256 cols, BK=32. A: fp32 [M][K] (AF32,
// LDS-staged, split in-register) or fp16 hi/lo planes. B: Wt[N][K] hi/lo.
// 3-product compensation (Ahi*Bhi + Ahi*Blo + Alo*Bhi, fp32 MFMA acc).
// 4 waves as 2x2; wave tile 64x128 (4 m-tiles x 8 n-tiles), acc[4][8].
// LDS XOR-swizzled at 16B granularity: fp16 rows (64B, rc=row&15):
// seg' = seg ^ ((rc>>1)&3); fp32 rows (128B, rc=row&7): seg' = seg ^ rc.
// Staging picks the swizzled global 16B per lane (DMA dest is lane*16 fixed).
// FINAL (N==256): epilogue computes bias+act then FUSED row softmax, writes
// probabilities. Else: bias+act to Chi/Clo fp16 planes.
template <bool AF32, bool FINAL>
__global__ __launch_bounds__(256, 2) void gemm_act(
    const float* __restrict__ Af, const _Float16* __restrict__ Ahi,
    const _Float16* __restrict__ Alo, const _Float16* __restrict__ Bhi,
    const _Float16* __restrict__ Blo, const float* __restrict__ bias,
    const float* __restrict__ ap, _Float16* __restrict__ Chi,
    _Float16* __restrict__ Clo, float* __restrict__ Cout, int K, int N) {
  // sA: 16 KB = fp32 128x32 (AF32) or 2 fp16 planes 128x32; sB: 32 KB
  __shared__ __align__(16) _Float16 sA[8192];
  __shared__ __align__(16) _Float16 sB[16384];

  const int tid = threadIdx.x;
  const int wv = tid >> 6;
  const int lane = tid & 63;
  const int wm = wv >> 1, wn = wv & 1;
  const int m16 = lane & 15, quad = lane >> 4;
  const int col0 = blockIdx.x * 256;
  const int row0 = blockIdx.y * 128;

  // staging lane decomposition + swizzled global seg
  const int rl4 = lane >> 2, sl4 = lane & 3;           // 16-row chunks (64B rows)
  const int sg4 = sl4 ^ ((rl4 >> 1) & 3);
  const int rl8 = lane >> 3, sl8 = lane & 7;           // 8-row chunks (128B rows)
  const int sg8 = sl8 ^ rl8;
  // fragment-read swizzle offsets (in halfs / floats)
  const int fswz = (quad ^ ((m16 >> 1) & 3)) * 8;      // fp16: 8 halfs per seg
  const int rc7 = m16 & 7;

  f32x4 acc[4][8];
  const f32x4 zero = {0.f, 0.f, 0.f, 0.f};
#pragma unroll
  for (int i = 0; i < 4; ++i)
#pragma unroll
    for (int j = 0; j < 8; ++j) acc[i][j] = zero;

  const int nk = K >> 5;
  for (int kt = 0; kt < nk; ++kt) {
    const int k0 = kt << 5;
    // ---- stage A ----
    if (AF32) {
      float* sAf = (float*)sA;
#pragma unroll
      for (int t = 0; t < 4; ++t) {
        const int c = wv * 4 + t;                       // 16 chunks of 8 rows
        const size_t ga = (size_t)(row0 + c * 8 + rl8) * K + k0 + sg8 * 4;
        async_ld16(Af + ga, (void*)&sAf[c * 256]);
      }
    } else {
#pragma unroll
      for (int t = 0; t < 2; ++t) {
        const int c = wv * 2 + t;                       // 8 chunks of 16 rows
        const size_t ga = (size_t)(row0 + c * 16 + rl4) * K + k0 + sg4 * 8;
        async_ld16(Ahi + ga, (void*)&sA[c * 512]);
        async_ld16(Alo + ga, (void*)&sA[4096 + c * 512]);
      }
    }
    // ---- stage B: 16 chunks of 16 cols per plane ----
#pragma unroll
    for (int t = 0; t < 4; ++t) {
      const int c = wv * 4 + t;
      const size_t gb = (size_t)(col0 + c * 16 + rl4) * K + k0 + sg4 * 8;
      async_ld16(Bhi + gb, (void*)&sB[c * 512]);
      async_ld16(Blo + gb, (void*)&sB[8192 + c * 512]);
    }
    __syncthreads();

    // ---- A fragments ----
    f16x8 ah[4], al[4];
#pragma unroll
    for (int tm = 0; tm < 4; ++tm) {
      if (AF32) {
        const int chunk = wm * 8 + tm * 2 + (m16 >> 3);
        const float* sAf = (const float*)sA + chunk * 256 + rc7 * 32;
        const f32x4 x0 = *(const f32x4*)(sAf + ((2 * quad) ^ rc7) * 4);
        const f32x4 x1 = *(const f32x4*)(sAf + ((2 * quad + 1) ^ rc7) * 4);
#pragma unroll
        for (int j = 0; j < 4; ++j) {
          const _Float16 h0 = (_Float16)x0[j];
          ah[tm][j] = h0;
          al[tm][j] = (_Float16)(x0[j] - (float)h0);
          const _Float16 h1 = (_Float16)x1[j];
          ah[tm][4 + j] = h1;
          al[tm][4 + j] = (_Float16)(x1[j] - (float)h1);
        }
      } else {
        const int idx = (wm * 4 + tm) * 512 + m16 * 32 + fswz;
        ah[tm] = *(const f16x8*)&sA[idx];
        al[tm] = *(const f16x8*)&sA[4096 + idx];
      }
    }
    // ---- B fragments + MFMA ----
#pragma unroll
    for (int tn = 0; tn < 8; ++tn) {
      const int idx = (wn * 8 + tn) * 512 + m16 * 32 + fswz;
      const f16x8 bh = *(const f16x8*)&sB[idx];
      const f16x8 bl = *(const f16x8*)&sB[8192 + idx];
#pragma unroll
      for (int tm = 0; tm < 4; ++tm)
        acc[tm][tn] = mfma3(ah[tm], al[tm], bh, bl, acc[tm][tn]);
    }
    __syncthreads();
  }

  if (!FINAL) {
    // ---- epilogue: bias + act -> hi/lo planes. C/D: col=lane&15, row=quad*4+reg
#pragma unroll
    for (int tn = 0; tn < 8; ++tn) {
      const int col = col0 + wn * 128 + tn * 16 + m16;
      const float bs = bias[col];
      const float p0 = ap[col * 5 + 0];
      const float p1 = ap[col * 5 + 1];
      const float p2 = ap[col * 5 + 2];
      const float p3 = ap[col * 5 + 3];
      const float p4 = ap[col * 5 + 4];
#pragma unroll
      for (int tm = 0; tm < 4; ++tm) {
        const int row = row0 + wm * 64 + tm * 16 + quad * 4;
#pragma unroll
        for (int r = 0; r < 4; ++r) {
          const float y = act_f(acc[tm][tn][r] + bs, p0, p1, p2, p3, p4);
          const size_t o = (size_t)(row + r) * N + col;
          const _Float16 h = (_Float16)y;
          Chi[o] = h;
          Clo[o] = (_Float16)(y - (float)h);
        }
      }
    }
  } else {
    // ---- epilogue: bias + act + FUSED softmax over 256 cols ----
    const float L2E = 1.4426950408889634f;
    float mx[16], sm[16];
#pragma unroll
    for (int i = 0; i < 16; ++i) mx[i] = -1e30f;
    // pass 1: y into acc, per-lane row max over tn
#pragma unroll
    for (int tn = 0; tn < 8; ++tn) {
      const int col = wn * 128 + tn * 16 + m16;
      const float bs = bias[col];
      const float p0 = ap[col * 5 + 0];
      const float p1 = ap[col * 5 + 1];
      const float p2 = ap[col * 5 + 2];
      const float p3 = ap[col * 5 + 3];
      const float p4 = ap[col * 5 + 4];
#pragma unroll
      for (int tm = 0; tm < 4; ++tm)
#pragma unroll
        for (int r = 0; r < 4; ++r) {
          const float y = act_f(acc[tm][tn][r] + bs, p0, p1, p2, p3, p4);
          acc[tm][tn][r] = y;
          mx[tm * 4 + r] = fmaxf(mx[tm * 4 + r], y);
        }
    }
    // butterfly max within the 16-lane (m16) group
#pragma unroll
    for (int i = 0; i < 16; ++i)
#pragma unroll
      for (int off = 1; off < 16; off <<= 1)
        mx[i] = fmaxf(mx[i], __shfl_xor(mx[i], off));
    // exp + per-lane sum
#pragma unroll
    for (int i = 0; i < 16; ++i) sm[i] = 0.f;
#pragma unroll
    for (int tn = 0; tn < 8; ++tn)
#pragma unroll
      for (int tm = 0; tm < 4; ++tm)
#pragma unroll
        for (int r = 0; r < 4; ++r) {
          const float e = __builtin_amdgcn_exp2f(
              (acc[tm][tn][r] - mx[tm * 4 + r]) * L2E);
          acc[tm][tn][r] = e;
          sm[tm * 4 + r] += e;
        }
#pragma unroll
    for (int i = 0; i < 16; ++i)
#pragma unroll
      for (int off = 1; off < 16; off <<= 1) sm[i] += __shfl_xor(sm[i], off);
    // cross-wave (wn pair) combine via 2 KB LDS: part[wn][row][{max,sum}]
    float* part = (float*)sA;
    if (m16 == 0) {
#pragma unroll
      for (int tm = 0; tm < 4; ++tm)
#pragma unroll
        for (int r = 0; r < 4; ++r) {
          const int row = wm * 64 + tm * 16 + quad * 4 + r;
          part[(wn * 128 + row) * 2 + 0] = mx[tm * 4 + r];
          part[(wn * 128 + row) * 2 + 1] = sm[tm * 4 + r];
        }
    }
    __syncthreads();
    float sc[16];
#pragma unroll
    for (int tm = 0; tm < 4; ++tm)
#pragma unroll
      for (int r = 0; r < 4; ++r) {
        const int i = tm * 4 + r;
        const int row = wm * 64 + tm * 16 + quad * 4 + r;
        const float mo = part[((1 - wn) * 128 + row) * 2 + 0];
        const float so = part[((1 - wn) * 128 + row) * 2 + 1];
        const float M = fmaxf(mx[i], mo);
        const float a = __builtin_amdgcn_exp2f((mx[i] - M) * L2E);
        const float b = __builtin_amdgcn_exp2f((mo - M) * L2E);
        sc[i] = a * __builtin_amdgcn_rcpf(fmaf(sm[i], a, so * b));
      }
#pragma unroll
    for (int tn = 0; tn < 8; ++tn) {
      const int col = wn * 128 + tn * 16 + m16;
#pragma unroll
      for (int tm = 0; tm < 4; ++tm) {
        const int row = row0 + wm * 64 + tm * 16 + quad * 4;
#pragma unroll
        for (int r = 0; r < 4; ++r)
          Cout[(size_t)(row + r) * 256 + col] = acc[tm][tn][r] * sc[tm * 4 + r];
      }
    }
  }
}

extern "C" void kernel_launch(void* const* d_in, const int* in_sizes, int n_in,
                              void* d_out, int out_size, void* d_ws,
                              size_t ws_size, hipStream_t stream) {
  const float* data = (const float*)d_in[0];
  const float* W1 = (const float*)d_in[1];
  const float* b1 = (const float*)d_in[2];
  const float* a1 = (const float*)d_in[3];
  const float* W2 = (const float*)d_in[4];
  const float* b2 = (const float*)d_in[5];
  const float* a2 = (const float*)d_in[6];
  const float* W3 = (const float*)d_in[7];
  const float* b3 = (const float*)d_in[8];
  const float* a3 = (const float*)d_in[9];
  float* out = (float*)d_out;

  char* ws = (char*)d_ws;
  const size_t KB = 1024, MB = 1024 * 1024;
  _Float16* w1hi = (_Float16*)(ws + 0 * KB);     // Wt1[512][256]
  _Float16* w1lo = (_Float16*)(ws + 256 * KB);
  _Float16* w2hi = (_Float16*)(ws + 512 * KB);   // Wt2[512][512]
  _Float16* w2lo = (_Float16*)(ws + 1024 * KB);
  _Float16* w3hi = (_Float16*)(ws + 1536 * KB);  // Wt3[256][512]
  _Float16* w3lo = (_Float16*)(ws + 1792 * KB);
  // h1 hi/lo: 64 MB each; h2lo 64 MB; h2hi aliases d_out (row i of h2hi =
  // bytes [1024i,1024i+1024) = out row i; GEMM3 blocks are full-N and
  // row-disjoint, reads finish before the epilogue writes -> alias-safe)
  _Float16* h1hi = (_Float16*)(ws + 2 * MB);
  _Float16* h1lo = (_Float16*)(ws + 2 * MB + (size_t)BATCH * 512 * 2);
  _Float16* h2lo = (_Float16*)(ws + 2 * MB + (size_t)BATCH * 512 * 4);
  _Float16* h2hi = (_Float16*)d_out;

  splitT_k<<<(256 * 512 + 255) / 256, 256, 0, stream>>>(W1, w1hi, w1lo, 256, 512);
  splitT_k<<<(512 * 512 + 255) / 256, 256, 0, stream>>>(W2, w2hi, w2lo, 512, 512);
  splitT_k<<<(512 * 256 + 255) / 256, 256, 0, stream>>>(W3, w3hi, w3lo, 512, 256);

  // grid: x = N-tiles (fastest -> strip-mates adjacent, L3-hot A), y = M-strips
  gemm_act<true, false><<<dim3(2, BATCH / 128), 256, 0, stream>>>(
      data, nullptr, nullptr, w1hi, w1lo, b1, a1, h1hi, h1lo, nullptr, 256, 512);
  gemm_act<false, false><<<dim3(2, BATCH / 128), 256, 0, stream>>>(
      nullptr, h1hi, h1lo, w2hi, w2lo, b2, a2, h2hi, h2lo, nullptr, 512, 512);
  gemm_act<false, true><<<dim3(1, BATCH / 128), 256, 0, stream>>>(
      nullptr, h2hi, h2lo, w3hi, w3lo, b3, a3, nullptr, nullptr, out, 512, 256);
}